// Round 1
// baseline (279.908 us; speedup 1.0000x reference)
//
#include <hip/hip_runtime.h>
#include <math.h>

// TopKRouter: logits = x(16384x2048) @ W(2048x64) + b; softmax over E=64; top-2.
// Output layout: d_out[0:32768] = topk indices (as float), d_out[32768:65536] = topk probs.

#define D_DIM 2048
#define E_DIM 64
#define M_DIM 16384
#define BM 64
#define BK 32

__global__ __launch_bounds__(256) void topk_router_kernel(
    const float* __restrict__ x, const float* __restrict__ Wm,
    const float* __restrict__ bias, float* __restrict__ out)
{
    __shared__ float xs[BK][BM];          // x tile, transposed: xs[k][m]
    __shared__ float ws[BK][E_DIM];       // W tile: ws[k][e]
    __shared__ float lg[BM][E_DIM + 1];   // logits, +1 pad to break bank stride
    __shared__ float bs[E_DIM];

    const int tid = threadIdx.x;
    const int m0  = blockIdx.x * BM;

    // compute-phase thread tile: 4 rows x 4 experts
    const int tr = tid >> 4;    // 0..15 -> rows tr*4 .. tr*4+3
    const int tc = tid & 15;    // 0..15 -> experts tc*4 .. tc*4+3

    // staging indices
    const int xm = tid >> 2;          // 0..63: row within tile
    const int xk = (tid & 3) * 8;     // 0,8,16,24: k offset (loads 8 floats)
    const int wk = tid >> 3;          // 0..31: k row of W tile
    const int we = (tid & 7) * 8;     // 0..56: e offset (loads 8 floats)

    if (tid < E_DIM) bs[tid] = bias[tid];

    float acc[4][4] = {};

    const float* xrow = x + (size_t)(m0 + xm) * D_DIM;

    for (int k0 = 0; k0 < D_DIM; k0 += BK) {
        // global loads (16B vectorized, coalesced)
        float4 xa = *reinterpret_cast<const float4*>(xrow + k0 + xk);
        float4 xb = *reinterpret_cast<const float4*>(xrow + k0 + xk + 4);
        float4 wa = *reinterpret_cast<const float4*>(Wm + (size_t)(k0 + wk) * E_DIM + we);
        float4 wb = *reinterpret_cast<const float4*>(Wm + (size_t)(k0 + wk) * E_DIM + we + 4);

        __syncthreads();   // previous iteration's readers done before overwrite

        float xq[8] = {xa.x, xa.y, xa.z, xa.w, xb.x, xb.y, xb.z, xb.w};
        #pragma unroll
        for (int q = 0; q < 8; q++) xs[xk + q][xm] = xq[q];
        *reinterpret_cast<float4*>(&ws[wk][we])     = wa;
        *reinterpret_cast<float4*>(&ws[wk][we + 4]) = wb;

        __syncthreads();

        #pragma unroll
        for (int kk = 0; kk < BK; kk++) {
            float4 t1 = *reinterpret_cast<const float4*>(&xs[kk][tr * 4]);
            float4 t2 = *reinterpret_cast<const float4*>(&ws[kk][tc * 4]);
            float xv[4] = {t1.x, t1.y, t1.z, t1.w};
            float wv[4] = {t2.x, t2.y, t2.z, t2.w};
            #pragma unroll
            for (int i = 0; i < 4; i++)
                #pragma unroll
                for (int j = 0; j < 4; j++)
                    acc[i][j] = fmaf(xv[i], wv[j], acc[i][j]);
        }
    }

    // logits (+bias) to LDS
    #pragma unroll
    for (int i = 0; i < 4; i++)
        #pragma unroll
        for (int j = 0; j < 4; j++)
            lg[tr * 4 + i][tc * 4 + j] = acc[i][j] + bs[tc * 4 + j];
    __syncthreads();

    // epilogue: one lane per row (wave 0 only); softmax + top-2 with
    // jax tie-break semantics (strict >, ascending scan -> lowest index wins).
    if (tid < BM) {
        const int row = tid;
        float mx = -INFINITY;
        #pragma unroll 8
        for (int e = 0; e < E_DIM; e++) mx = fmaxf(mx, lg[row][e]);

        float s = 0.f;
        #pragma unroll 8
        for (int e = 0; e < E_DIM; e++) s += expf(lg[row][e] - mx);

        float v1 = -1.f, v2 = -1.f;
        int   i1 = 0,    i2 = 0;
        for (int e = 0; e < E_DIM; e++) {
            float p = expf(lg[row][e] - mx) / s;   // final prob, same form as ref
            if (p > v1)      { v2 = v1; i2 = i1; v1 = p; i1 = e; }
            else if (p > v2) { v2 = p; i2 = e; }
        }

        const int gr = m0 + row;
        out[gr * 2 + 0] = (float)i1;
        out[gr * 2 + 1] = (float)i2;
        out[M_DIM * 2 + gr * 2 + 0] = v1;
        out[M_DIM * 2 + gr * 2 + 1] = v2;
    }
}

extern "C" void kernel_launch(void* const* d_in, const int* in_sizes, int n_in,
                              void* d_out, int out_size, void* d_ws, size_t ws_size,
                              hipStream_t stream) {
    const float* x  = (const float*)d_in[0];
    const float* Wm = (const float*)d_in[1];
    const float* b  = (const float*)d_in[2];
    float* out = (float*)d_out;

    dim3 grid(M_DIM / BM);   // 256 blocks
    dim3 block(256);
    topk_router_kernel<<<grid, block, 0, stream>>>(x, Wm, b, out);
}